// Round 7
// baseline (2951.354 us; speedup 1.0000x reference)
//
#include <hip/hip_runtime.h>

// SplineConv MI355X (gfx950). fp32 in/out. R7: decomposed pipeline for attribution.
//   main path (ws >= ~321 MB):
//     k_wt (wt[o][1600] bf16) ; memset deg ; k_deg ; memset acc[N*25*64] fp32 ;
//     k_root (out = x@root + bias) ; k_scatter (global-atomic edge scatter) ;
//     k_gemm (out += acc@wt / deg, MFMA)
//   fallback (small ws): R6 LDS-fused path (known correct, slow).

#define NN   50000
#define EE   1600000
#define KC   1600            // 25*64 conv K
#define NPB  16              // fallback path
#define KD   1664
#define AST  1668
#define GRP  8

typedef unsigned short ushort_t;
typedef __attribute__((ext_vector_type(8))) short short8;
typedef __attribute__((ext_vector_type(4))) float f32x4;

static __device__ __forceinline__ ushort_t f2bf(float f) {
  union { float f; unsigned u; } v; v.f = f;
  return (ushort_t)((v.u + 0x7fffu + ((v.u >> 16) & 1u)) >> 16);  // RNE
}

// ---------------- K: wt[o*1600+k] = bf16(weight[k*64+o])
__global__ void k_wt(const float* __restrict__ w, ushort_t* __restrict__ wt) {
  int idx = blockIdx.x * 256 + threadIdx.x;          // over 64*1600
  if (idx >= 64 * KC) return;
  int o = idx / KC, k = idx - o * KC;
  wt[idx] = f2bf(w[k * 64 + o]);
}

// ---------------- K: degree count
__global__ void k_deg(const int* __restrict__ ei, int* __restrict__ deg) {
  int e = blockIdx.x * 256 + threadIdx.x;
  if (e < EE) atomicAdd(&deg[ei[e]], 1);
}

// ---------------- K: out[n][o] = bias[o] + x[n]@root[:,o]   (exact fp32)
__global__ __launch_bounds__(256) void k_root(const float* __restrict__ x,
                                              const float* __restrict__ root,
                                              const float* __restrict__ bias,
                                              float* __restrict__ out) {
  int t = blockIdx.x * 256 + threadIdx.x;            // 3.2M threads
  int n = t >> 6, o = t & 63;
  if (n >= NN) return;
  const float* xr = x + (size_t)n * 64;
  float s0 = bias[o], s1 = 0.f, s2 = 0.f, s3 = 0.f;
  for (int i = 0; i < 64; i += 4) {
    s0 += xr[i]     * root[(i)     * 64 + o];
    s1 += xr[i + 1] * root[(i + 1) * 64 + o];
    s2 += xr[i + 2] * root[(i + 2) * 64 + o];
    s3 += xr[i + 3] * root[(i + 3) * 64 + o];
  }
  out[(size_t)n * 64 + o] = (s0 + s1) + (s2 + s3);
}

// ---------------- K: edge-parallel scatter into global acc[(n*25+kp)*64+i], fp32 HW atomics
__global__ __launch_bounds__(256) void k_scatter(const int* __restrict__ ei,
                                                 const float* __restrict__ pseudo,
                                                 const float* __restrict__ x,
                                                 float* __restrict__ acc) {
  const int lane = threadIdx.x & 63;
  const int gw = blockIdx.x * 4 + (threadIdx.x >> 6);   // 8192 waves
  const int C = (EE + 8191) / 8192;                     // 196 edges per wave
  const int s = gw * C;
  const int epnd = min(s + C, EE);
  for (int e0 = s; e0 < epnd; e0 += 4) {
    int row4[4], col4[4], kb4[4];
    float w0[4], w1[4], w2[4], w3[4];
#pragma unroll
    for (int j = 0; j < 4; ++j) {
      int e = e0 + j; e = (e < EE) ? e : (EE - 1);
      row4[j] = ei[e];                                  // wave-uniform broadcast loads
      col4[j] = ei[EE + e];
      float v0 = pseudo[2 * (size_t)e] * 4.0f;
      float v1 = pseudo[2 * (size_t)e + 1] * 4.0f;
      int lo0 = min((int)v0, 3), lo1 = min((int)v1, 3);
      float fr0 = v0 - (float)lo0, fr1 = v1 - (float)lo1;
      float g0 = 1.0f - fr0, g1 = 1.0f - fr1;
      w0[j] = g0 * g1;  w1[j] = g0 * fr1;
      w2[j] = fr0 * g1; w3[j] = fr0 * fr1;
      kb4[j] = lo0 * 5 + lo1;
    }
    float xs[4];
#pragma unroll
    for (int j = 0; j < 4; ++j) xs[j] = x[(size_t)col4[j] * 64 + lane];
#pragma unroll
    for (int j = 0; j < 4; ++j) {
      if (e0 + j < epnd) {                              // wave-uniform branch
        float* ap = acc + ((size_t)row4[j] * 25 + kb4[j]) * 64 + lane;
        unsafeAtomicAdd(ap,       w0[j] * xs[j]);       // global_atomic_add_f32, no return
        unsafeAtomicAdd(ap + 64,  w1[j] * xs[j]);
        unsafeAtomicAdd(ap + 320, w2[j] * xs[j]);
        unsafeAtomicAdd(ap + 384, w3[j] * xs[j]);
      }
    }
  }
}

// ---------------- K: out[n][o] += (acc[n] @ wt[o]) / max(deg,1).  MFMA, A streamed.
__global__ __launch_bounds__(256) void k_gemm(const float* __restrict__ acc,
                                              const ushort_t* __restrict__ wt,
                                              const int* __restrict__ deg,
                                              float* __restrict__ out) {
  const int lane = threadIdx.x & 63, wv = threadIdx.x >> 6;
  const int nb = blockIdx.x * 64 + wv * 16;            // 16 nodes per wave
  const int m = lane & 15, quad = lane >> 4;
  const int arow = min(nb + m, NN - 1);
  const float*    ab = acc + (size_t)arow * KC + quad * 8;
  const ushort_t* wb = wt + (size_t)m * KC + quad * 8; // + ct*16*KC per out-tile
  f32x4 d0 = {0.f,0.f,0.f,0.f}, d1 = d0, d2 = d0, d3 = d0;
  for (int kb = 0; kb < KC; kb += 32) {
    float4 a0 = *(const float4*)(ab + kb);
    float4 a1 = *(const float4*)(ab + kb + 4);
    short8 af;
    af[0] = (short)f2bf(a0.x); af[1] = (short)f2bf(a0.y);
    af[2] = (short)f2bf(a0.z); af[3] = (short)f2bf(a0.w);
    af[4] = (short)f2bf(a1.x); af[5] = (short)f2bf(a1.y);
    af[6] = (short)f2bf(a1.z); af[7] = (short)f2bf(a1.w);
    short8 b0 = *(const short8*)(wb + kb);
    short8 b1 = *(const short8*)(wb + 16 * KC + kb);
    short8 b2 = *(const short8*)(wb + 32 * KC + kb);
    short8 b3 = *(const short8*)(wb + 48 * KC + kb);
    d0 = __builtin_amdgcn_mfma_f32_16x16x32_bf16(af, b0, d0, 0, 0, 0);
    d1 = __builtin_amdgcn_mfma_f32_16x16x32_bf16(af, b1, d1, 0, 0, 0);
    d2 = __builtin_amdgcn_mfma_f32_16x16x32_bf16(af, b2, d2, 0, 0, 0);
    d3 = __builtin_amdgcn_mfma_f32_16x16x32_bf16(af, b3, d3, 0, 0, 0);
  }
  // D layout [m89/m91]: col(j of B-tile)=lane&15, row(i of A-tile)=quad*4+reg
#pragma unroll
  for (int r = 0; r < 4; ++r) {
    int node = nb + quad * 4 + r;
    if (node < NN) {
      float fd = fmaxf((float)deg[node], 1.0f);
      float siv = 1.0f / fd;
      float* orow = out + (size_t)node * 64;
      orow[m]      += d0[r] * siv;
      orow[16 + m] += d1[r] * siv;
      orow[32 + m] += d2[r] * siv;
      orow[48 + m] += d3[r] * siv;
    }
  }
}

// ================= fallback path (R6, known-correct) =================
__global__ __launch_bounds__(1024) void k_scan(const int* __restrict__ deg,
                                               int* __restrict__ rowptr,
                                               int* __restrict__ cursor) {
  __shared__ int wsum[16];
  __shared__ int carry;
  const int t = threadIdx.x, lane = t & 63, wid = t >> 6;
  if (t == 0) carry = 0;
  __syncthreads();
  for (int base = 0; base < NN; base += 1024) {
    int i = base + t;
    int v = (i < NN) ? deg[i] : 0;
    int s = v;
    for (int off = 1; off < 64; off <<= 1) {
      int u = __shfl_up(s, off);
      if (lane >= off) s += u;
    }
    if (lane == 63) wsum[wid] = s;
    __syncthreads();
    int woff = 0;
    for (int j = 0; j < 16; ++j) { if (j < wid) woff += wsum[j]; }
    int c = carry;
    if (i < NN) { int ex = c + woff + s - v; rowptr[i] = ex; cursor[i] = ex; }
    __syncthreads();
    if (t == 1023) carry = c + woff + s;
    __syncthreads();
  }
  if (threadIdx.x == 0) rowptr[NN] = carry;
}

__global__ void k_rec(const int* __restrict__ ei, const float* __restrict__ pseudo,
                      int* __restrict__ cursor, uint4* __restrict__ recs) {
  int e = blockIdx.x * 256 + threadIdx.x;
  if (e >= EE) return;
  int row = ei[e], col = ei[EE + e];
  float v0 = pseudo[2 * (long)e] * 4.0f;
  float v1 = pseudo[2 * (long)e + 1] * 4.0f;
  int lo0 = min((int)v0, 3), lo1 = min((int)v1, 3);
  float fr0 = v0 - (float)lo0, fr1 = v1 - (float)lo1;
  int base = lo0 * 5 + lo1;
  int ln = row & (NPB - 1);
  int slot = atomicAdd(&cursor[row], 1);
  uint4 r;
  r.x = (unsigned)col;
  r.y = (unsigned)(ln | (base << 8));
  r.z = __float_as_uint(fr0);
  r.w = __float_as_uint(fr1);
  recs[slot] = r;
}

__global__ void k_wt_old(const float* __restrict__ w, ushort_t* __restrict__ wt) {
  int idx = blockIdx.x * 256 + threadIdx.x;
  if (idx >= 64 * KD) return;
  int o = idx / KD, k = idx - o * KD;
  wt[idx] = (k < 1600) ? f2bf(w[k * 64 + o]) : (ushort_t)0;
}

__global__ __launch_bounds__(1024) void k_main_lds(
    const uint4* __restrict__ recs, const int* __restrict__ rowptr,
    const float* __restrict__ x, const ushort_t* __restrict__ wt,
    const float* __restrict__ root, const float* __restrict__ bias,
    float* __restrict__ out) {
  __shared__ float acc[NPB * AST];
  __shared__ float outb[NPB * 64];
  __shared__ float sinv[NPB];
  const int tid = threadIdx.x;
  const int nb = blockIdx.x * NPB;
  const int lane = tid & 63;
  const int ln0 = tid >> 6;
  {
    float4* a4 = (float4*)acc;
    const float4 z = make_float4(0.f, 0.f, 0.f, 0.f);
    for (int j = tid; j < (NPB * AST) / 4; j += 1024) a4[j] = z;
    ((float4*)outb)[tid & 255] = z;
  }
  if (lane == 0) {
    int node = nb + ln0;
    int dc = max(rowptr[node + 1] - rowptr[node], 1);
    sinv[ln0] = 1.0f / (float)dc;
  }
  const int wid = __builtin_amdgcn_readfirstlane(tid >> 6);
  const int eBeg = rowptr[nb], eEnd = rowptr[nb + NPB];
  __syncthreads();
  {
    const int total = eEnd - eBeg;
    const int C = (total + NPB - 1) >> 4;
    const int cb = eBeg + wid * C;
    const int ce = min(cb + C, eEnd);
    for (int g = cb; g < ce; g += GRP) {
      uint4 rg[GRP];
#pragma unroll
      for (int j = 0; j < GRP; ++j) {
        int e = g + j; e = (e < EE) ? e : (EE - 1);
        rg[j] = recs[e];
      }
      float xs[GRP], w0[GRP], w1[GRP], w2[GRP], w3[GRP];
      int ofs[GRP];
#pragma unroll
      for (int j = 0; j < GRP; ++j) {
        int col = (int)rg[j].x;
        int l2  = (int)(rg[j].y & 255u);
        int bs  = (int)(rg[j].y >> 8);
        float fr0 = __uint_as_float(rg[j].z);
        float fr1 = __uint_as_float(rg[j].w);
        float mk  = (g + j < ce) ? 1.0f : 0.0f;
        float g0 = 1.0f - fr0, g1 = 1.0f - fr1;
        w0[j] = g0 * g1 * mk;  w1[j] = g0 * fr1 * mk;
        w2[j] = fr0 * g1 * mk; w3[j] = fr0 * fr1 * mk;
        ofs[j] = l2 * AST + (bs << 6);
        xs[j] = x[(size_t)col * 64 + lane];
      }
#pragma unroll
      for (int j = 0; j < GRP; ++j) {
        float* ap = &acc[ofs[j] + lane];
        float v = xs[j];
        unsafeAtomicAdd(ap,       w0[j] * v);
        unsafeAtomicAdd(ap + 64,  w1[j] * v);
        unsafeAtomicAdd(ap + 320, w2[j] * v);
        unsafeAtomicAdd(ap + 384, w3[j] * v);
      }
    }
  }
  __syncthreads();
  {
    const int ntile = wid & 3, kh = wid >> 2;
    const int m = lane & 15, quad = lane >> 4;
    const int nn2 = ntile * 16 + m;
    f32x4 d = {0.0f, 0.0f, 0.0f, 0.0f};
    const float*    ab = &acc[m * AST + kh * 416 + quad * 8];
    const ushort_t* wb = &wt[(size_t)nn2 * KD + kh * 416 + quad * 8];
    for (int kk = 0; kk < 13; ++kk) {
      float4 a0 = *(const float4*)(ab + kk * 32);
      float4 a1 = *(const float4*)(ab + kk * 32 + 4);
      short8 af;
      af[0] = (short)f2bf(a0.x); af[1] = (short)f2bf(a0.y);
      af[2] = (short)f2bf(a0.z); af[3] = (short)f2bf(a0.w);
      af[4] = (short)f2bf(a1.x); af[5] = (short)f2bf(a1.y);
      af[6] = (short)f2bf(a1.z); af[7] = (short)f2bf(a1.w);
      short8 bf = *(const short8*)(wb + kk * 32);
      d = __builtin_amdgcn_mfma_f32_16x16x32_bf16(af, bf, d, 0, 0, 0);
    }
    float* ob = &outb[ntile * 16 + m];
    int r0 = quad * 4;
    unsafeAtomicAdd(ob + (r0 + 0) * 64, d[0]);
    unsafeAtomicAdd(ob + (r0 + 1) * 64, d[1]);
    unsafeAtomicAdd(ob + (r0 + 2) * 64, d[2]);
    unsafeAtomicAdd(ob + (r0 + 3) * 64, d[3]);
  }
  __syncthreads();
  {
    const int node = nb + ln0;
    const float* xrow = &x[(size_t)node * 64];
    float r0 = bias[lane], r1 = 0.f, r2 = 0.f, r3 = 0.f;
    for (int i = 0; i < 64; i += 4) {
      r0 += xrow[i]     * root[(size_t)i * 64 + lane];
      r1 += xrow[i + 1] * root[(size_t)(i + 1) * 64 + lane];
      r2 += xrow[i + 2] * root[(size_t)(i + 2) * 64 + lane];
      r3 += xrow[i + 3] * root[(size_t)(i + 3) * 64 + lane];
    }
    out[(size_t)node * 64 + lane] = outb[tid] * sinv[ln0] + ((r0 + r1) + (r2 + r3));
  }
}

extern "C" void kernel_launch(void* const* d_in, const int* in_sizes, int n_in,
                              void* d_out, int out_size, void* d_ws, size_t ws_size,
                              hipStream_t stream) {
  const float* x      = (const float*)d_in[0];
  const int*   ei     = (const int*)d_in[1];
  const float* pseudo = (const float*)d_in[2];
  const float* w      = (const float*)d_in[3];
  const float* root   = (const float*)d_in[4];
  const float* bias   = (const float*)d_in[5];
  float* out = (float*)d_out;
  (void)in_sizes; (void)n_in; (void)out_size;

  char* ws = (char*)d_ws;
  const size_t accB = (size_t)NN * 25 * 64 * 4;        // 320 MB
  const size_t mainNeed = accB + (size_t)64 * KC * 2 + (size_t)NN * 4 + 4096;

  if (ws_size >= mainNeed) {
    float*    acc = (float*)ws;
    ushort_t* wt  = (ushort_t*)(ws + accB);
    int*      deg = (int*)(ws + accB + ((size_t)64 * KC * 2 + 511) / 512 * 512);

    k_wt<<<(64 * KC + 255) / 256, 256, 0, stream>>>(w, wt);
    hipMemsetAsync(deg, 0, (size_t)NN * 4, stream);
    k_deg<<<(EE + 255) / 256, 256, 0, stream>>>(ei, deg);
    hipMemsetAsync(acc, 0, accB, stream);
    k_root<<<(NN * 64 + 255) / 256, 256, 0, stream>>>(x, root, bias, out);
    k_scatter<<<2048, 256, 0, stream>>>(ei, pseudo, x, acc);
    k_gemm<<<(NN + 63) / 64, 256, 0, stream>>>(acc, wt, deg, out);
    return;
  }

  // -------- fallback: R6 LDS-fused path --------
  size_t off = 0;
  auto alloc = [&](size_t bytes) { size_t r = off; off += (bytes + 511) & ~(size_t)511; return r; };
  ushort_t* wt     = (ushort_t*)(ws + alloc((size_t)64 * KD * 2));
  int*      rowptr = (int*)(ws + alloc((size_t)(NN + 1) * 4));
  int*      cursor = (int*)(ws + alloc((size_t)NN * 4));
  int*      deg    = (int*)(ws + alloc((size_t)NN * 4));
  uint4*    recs   = (uint4*)(ws + alloc((size_t)EE * 16));

  k_wt_old<<<(64 * KD + 255) / 256, 256, 0, stream>>>(w, wt);
  hipMemsetAsync(deg, 0, (size_t)NN * 4, stream);
  k_deg<<<(EE + 255) / 256, 256, 0, stream>>>(ei, deg);
  k_scan<<<1, 1024, 0, stream>>>(deg, rowptr, cursor);
  k_rec<<<(EE + 255) / 256, 256, 0, stream>>>(ei, pseudo, cursor, recs);
  k_main_lds<<<NN / NPB, 1024, 0, stream>>>(recs, rowptr, x, wt, root, bias, out);
}

// Round 8
// 643.598 us; speedup vs baseline: 4.5857x; 4.5857x over previous
//
#include <hip/hip_runtime.h>

// SplineConv MI355X (gfx950). fp32 in/out. R8: NO LDS atomics (Theory A: LDS atomic
// throughput ~256cyc/instr was the R5-R7 wall). One wave = one node; 25 kernel-slice
// partials in VGPRs (branchless 5x5 outer-product FMA); plain bf16 ds_writes into
// MFMA-A-layout tile; verified MFMA epilogue; kh-partials summed via disjoint LDS.
//
// Pipeline: k_wt (wt[o][1664] bf16, zero tail) ; memset deg ; k_deg ; k_scan ->
//   rowptr/cursor ; k_rec (16B recs by target node) ; k_main (fused, atomic-free).

#define NN   50000
#define EE   1600000
#define NPB  16
#define KD   1664            // 26*64: 25 conv slices + zero pad (MFMA k-multiple)
#define ASTB 1672            // accS row stride in bf16 elems (3344B; 2-way on b128 reads = free)

typedef unsigned short ushort_t;
typedef __attribute__((ext_vector_type(8))) short short8;
typedef __attribute__((ext_vector_type(4))) float f32x4;

static __device__ __forceinline__ ushort_t f2bf(float f) {
  union { float f; unsigned u; } v; v.f = f;
  return (ushort_t)((v.u + 0x7fffu + ((v.u >> 16) & 1u)) >> 16);  // RNE
}

// ---------------- K: wt[o*1664+k] = bf16(weight[k*64+o]) k<1600, else 0
__global__ void k_wt(const float* __restrict__ w, ushort_t* __restrict__ wt) {
  int idx = blockIdx.x * 256 + threadIdx.x;
  if (idx >= 64 * KD) return;
  int o = idx / KD, k = idx - o * KD;
  wt[idx] = (k < 1600) ? f2bf(w[k * 64 + o]) : (ushort_t)0;
}

// ---------------- K: degree count
__global__ void k_deg(const int* __restrict__ ei, int* __restrict__ deg) {
  int e = blockIdx.x * 256 + threadIdx.x;
  if (e < EE) atomicAdd(&deg[ei[e]], 1);
}

// ---------------- K: single-block exclusive scan -> rowptr[N+1], cursor[N]
__global__ __launch_bounds__(1024) void k_scan(const int* __restrict__ deg,
                                               int* __restrict__ rowptr,
                                               int* __restrict__ cursor) {
  __shared__ int wsum[16];
  __shared__ int carry;
  const int t = threadIdx.x, lane = t & 63, wid = t >> 6;
  if (t == 0) carry = 0;
  __syncthreads();
  for (int base = 0; base < NN; base += 1024) {
    int i = base + t;
    int v = (i < NN) ? deg[i] : 0;
    int s = v;
    for (int off = 1; off < 64; off <<= 1) {
      int u = __shfl_up(s, off);
      if (lane >= off) s += u;
    }
    if (lane == 63) wsum[wid] = s;
    __syncthreads();
    int woff = 0;
    for (int j = 0; j < 16; ++j) { if (j < wid) woff += wsum[j]; }
    int c = carry;
    if (i < NN) { int ex = c + woff + s - v; rowptr[i] = ex; cursor[i] = ex; }
    __syncthreads();
    if (t == 1023) carry = c + woff + s;
    __syncthreads();
  }
  if (threadIdx.x == 0) rowptr[NN] = carry;
}

// ---------------- K: 16B edge records {col, lo0|lo1<<8, fr0, fr1}
__global__ void k_rec(const int* __restrict__ ei, const float* __restrict__ pseudo,
                      int* __restrict__ cursor, uint4* __restrict__ recs) {
  int e = blockIdx.x * 256 + threadIdx.x;
  if (e >= EE) return;
  int row = ei[e], col = ei[EE + e];
  float v0 = pseudo[2 * (long)e] * 4.0f;
  float v1 = pseudo[2 * (long)e + 1] * 4.0f;
  int lo0 = min((int)v0, 3), lo1 = min((int)v1, 3);   // clamp == reference %K wrap (basis 0 there)
  float fr0 = v0 - (float)lo0, fr1 = v1 - (float)lo1;
  int slot = atomicAdd(&cursor[row], 1);
  uint4 r;
  r.x = (unsigned)col;
  r.y = (unsigned)(lo0 | (lo1 << 8));
  r.z = __float_as_uint(fr0);
  r.w = __float_as_uint(fr1);
  recs[slot] = r;
}

// ---------------- K: main fused. 1 block = 16 nodes; wave w owns node nb+w.
__global__ __launch_bounds__(1024) void k_main(
    const uint4* __restrict__ recs, const int* __restrict__ rowptr,
    const float* __restrict__ x, const ushort_t* __restrict__ wt,
    const float* __restrict__ root, const float* __restrict__ bias,
    float* __restrict__ out) {
  __shared__ ushort_t accS[NPB * ASTB];   // 53.5 KB, bf16, MFMA-A layout
  __shared__ float    outp[4 * NPB * 64]; // 16 KB, per-kh partials
  __shared__ float    sinv[NPB];
  const int tid = threadIdx.x;
  const int lane = tid & 63;
  const int w = tid >> 6;                 // wave id = node-in-block
  const int nb = blockIdx.x * NPB;
  const int node = nb + w;

  const int eb = rowptr[node], ee = rowptr[node + 1];
  if (lane == 0) sinv[w] = 1.0f / (float)max(ee - eb, 1);
  accS[w * ASTB + 1600 + lane] = 0;       // zero the MFMA k-pad slice

  float acc[25];
#pragma unroll
  for (int j = 0; j < 25; ++j) acc[j] = 0.0f;

  // per-node edge loop: register accumulation, zero atomics
  for (int e = eb; e < ee; ++e) {
    uint4 rc = recs[e];                   // wave-uniform 16B load
    const int   lo0 = (int)(rc.y & 255u), lo1 = (int)(rc.y >> 8);
    const float fr0 = __uint_as_float(rc.z), fr1 = __uint_as_float(rc.w);
    const float g0 = 1.0f - fr0, g1 = 1.0f - fr1;
    const float xs = x[(size_t)rc.x * 64 + lane];   // coalesced 256B row
    float wr[5], wc[5], p[5];
#pragma unroll
    for (int r = 0; r < 5; ++r)
      wr[r] = (r == lo0) ? g0 : ((r == lo0 + 1) ? fr0 : 0.0f);
#pragma unroll
    for (int c = 0; c < 5; ++c)
      wc[c] = (c == lo1) ? g1 : ((c == lo1 + 1) ? fr1 : 0.0f);
#pragma unroll
    for (int c = 0; c < 5; ++c) p[c] = wc[c] * xs;
#pragma unroll
    for (int r = 0; r < 5; ++r)
#pragma unroll
      for (int c = 0; c < 5; ++c)
        acc[r * 5 + c] = fmaf(wr[r], p[c], acc[r * 5 + c]);
  }

  // spill acc -> accS (plain bf16 stores, statically indexed)
#pragma unroll
  for (int kp = 0; kp < 25; ++kp)
    accS[w * ASTB + kp * 64 + lane] = f2bf(acc[kp]);
  __syncthreads();

  {  // MFMA epilogue: D[16 nodes][64 out] = accS[16][1664] @ wt^T
     // 16 waves = 4 n-tiles x 4 k-quarters (416 each = 13 MFMA)
    const int ntile = w & 3, kh = w >> 2;
    const int m = lane & 15, quad = lane >> 4;
    const int nn2 = ntile * 16 + m;
    f32x4 d = {0.0f, 0.0f, 0.0f, 0.0f};
    const ushort_t* ab = &accS[m * ASTB + kh * 416 + quad * 8];
    const ushort_t* wb = &wt[(size_t)nn2 * KD + kh * 416 + quad * 8];
    for (int kk = 0; kk < 13; ++kk) {
      short8 af = *(const short8*)(ab + kk * 32);    // ds_read_b128, A already bf16
      short8 bf = *(const short8*)(wb + kk * 32);
      d = __builtin_amdgcn_mfma_f32_16x16x32_bf16(af, bf, d, 0, 0, 0);
    }
    // D layout [m89/m91]: col(out-in-tile)=lane&15, row(node)=quad*4+reg
#pragma unroll
    for (int r = 0; r < 4; ++r)
      outp[kh * (NPB * 64) + (quad * 4 + r) * 64 + ntile * 16 + m] = d[r];
  }
  __syncthreads();

  {  // final: thread (w=node-in-block, lane=o); sum 4 kh partials, + exact fp32 root
    float conv = outp[0 * (NPB * 64) + w * 64 + lane]
               + outp[1 * (NPB * 64) + w * 64 + lane]
               + outp[2 * (NPB * 64) + w * 64 + lane]
               + outp[3 * (NPB * 64) + w * 64 + lane];
    const float* xrow = &x[(size_t)node * 64];
    float r0 = bias[lane], r1 = 0.f, r2 = 0.f, r3 = 0.f;
    for (int i = 0; i < 64; i += 4) {
      r0 += xrow[i]     * root[(size_t)i * 64 + lane];
      r1 += xrow[i + 1] * root[(size_t)(i + 1) * 64 + lane];
      r2 += xrow[i + 2] * root[(size_t)(i + 2) * 64 + lane];
      r3 += xrow[i + 3] * root[(size_t)(i + 3) * 64 + lane];
    }
    out[(size_t)node * 64 + lane] = conv * sinv[w] + ((r0 + r1) + (r2 + r3));
  }
}

// ---------------- sentinel: unambiguous "workspace too small" signature
__global__ void k_sentinel(float* __restrict__ out) {
  int i = blockIdx.x * 256 + threadIdx.x;
  if (i < NN * 64) out[i] = 1000.0f;
}

extern "C" void kernel_launch(void* const* d_in, const int* in_sizes, int n_in,
                              void* d_out, int out_size, void* d_ws, size_t ws_size,
                              hipStream_t stream) {
  const float* x      = (const float*)d_in[0];
  const int*   ei     = (const int*)d_in[1];
  const float* pseudo = (const float*)d_in[2];
  const float* w      = (const float*)d_in[3];
  const float* root   = (const float*)d_in[4];
  const float* bias   = (const float*)d_in[5];
  float* out = (float*)d_out;
  (void)in_sizes; (void)n_in; (void)out_size;

  char* ws = (char*)d_ws;
  size_t off = 0;
  auto alloc = [&](size_t bytes) { size_t r = off; off += (bytes + 511) & ~(size_t)511; return r; };
  ushort_t* wt     = (ushort_t*)(ws + alloc((size_t)64 * KD * 2));   // 212,992 B
  int*      rowptr = (int*)(ws + alloc((size_t)(NN + 1) * 4));
  int*      cursor = (int*)(ws + alloc((size_t)NN * 4));
  int*      deg    = (int*)(ws + alloc((size_t)NN * 4));
  uint4*    recs   = (uint4*)(ws + alloc((size_t)EE * 16));          // 25.6 MB
  if (ws_size < off) {  // ~26.4 MB needed (known available from R5/R6)
    k_sentinel<<<(NN * 64 + 255) / 256, 256, 0, stream>>>(out);
    return;
  }

  k_wt<<<(64 * KD + 255) / 256, 256, 0, stream>>>(w, wt);
  hipMemsetAsync(deg, 0, (size_t)NN * 4, stream);
  k_deg<<<(EE + 255) / 256, 256, 0, stream>>>(ei, deg);
  k_scan<<<1, 1024, 0, stream>>>(deg, rowptr, cursor);
  k_rec<<<(EE + 255) / 256, 256, 0, stream>>>(ei, pseudo, cursor, recs);
  k_main<<<NN / NPB, 1024, 0, stream>>>(recs, rowptr, x, wt, root, bias, out);
}

// Round 9
// 520.936 us; speedup vs baseline: 5.6655x; 1.2355x over previous
//
#include <hip/hip_runtime.h>
#include <hip/hip_bf16.h>

// SplineConv MI355X (gfx950). fp32 in/out. R9: scatter as MFMA tall-skinny GEMM.
// One wave = one node. Per 32-edge chunk: basis built analytically in A-fragment
// layout (hat(v)=max(0,1-|v-r|)), x gathered directly in B-fragment layout,
// 8x mfma_f32_16x16x32_bf16 accumulate acc[25(:32)][64] in VGPRs. No LDS ops in
// the hot loop (R8 lesson: LDS atomics ~256cyc; R8 VALU construction ~300cyc/edge).
// Operand/D layouts reused verbatim from the R8-validated epilogue.

#define NN   50000
#define EE   1600000
#define NPB  16
#define KD   1664            // 26*64: 25 conv slices + zero pad (MFMA k-multiple)
#define ASTB 1672            // accS row stride (bf16 elems)

typedef unsigned short ushort_t;
typedef __attribute__((ext_vector_type(8))) short short8;
typedef __attribute__((ext_vector_type(4))) float f32x4;

static __device__ __forceinline__ ushort_t f2bf(float f) {
  union { float f; unsigned u; } v; v.f = f;
  return (ushort_t)((v.u + 0x7fffu + ((v.u >> 16) & 1u)) >> 16);  // RNE
}
static __device__ __forceinline__ unsigned pk2bf(float a, float b) {
  __hip_bfloat162 h = __float22bfloat162_rn(make_float2(a, b));   // v_cvt_pk_bf16_f32
  union { __hip_bfloat162 h; unsigned u; } cv; cv.h = h; return cv.u;
}
union S8 { short8 s; unsigned u[4]; };

// ---------------- K: wt[o*1664+k] = bf16(weight[k*64+o]) k<1600, else 0
__global__ void k_wt(const float* __restrict__ w, ushort_t* __restrict__ wt) {
  int idx = blockIdx.x * 256 + threadIdx.x;
  if (idx >= 64 * KD) return;
  int o = idx / KD, k = idx - o * KD;
  wt[idx] = (k < 1600) ? f2bf(w[k * 64 + o]) : (ushort_t)0;
}

// ---------------- K: degree count
__global__ void k_deg(const int* __restrict__ ei, int* __restrict__ deg) {
  int e = blockIdx.x * 256 + threadIdx.x;
  if (e < EE) atomicAdd(&deg[ei[e]], 1);
}

// ---------------- K: single-block exclusive scan -> rowptr[N+1], cursor[N]
__global__ __launch_bounds__(1024) void k_scan(const int* __restrict__ deg,
                                               int* __restrict__ rowptr,
                                               int* __restrict__ cursor) {
  __shared__ int wsum[16];
  __shared__ int carry;
  const int t = threadIdx.x, lane = t & 63, wid = t >> 6;
  if (t == 0) carry = 0;
  __syncthreads();
  for (int base = 0; base < NN; base += 1024) {
    int i = base + t;
    int v = (i < NN) ? deg[i] : 0;
    int s = v;
    for (int off = 1; off < 64; off <<= 1) {
      int u = __shfl_up(s, off);
      if (lane >= off) s += u;
    }
    if (lane == 63) wsum[wid] = s;
    __syncthreads();
    int woff = 0;
    for (int j = 0; j < 16; ++j) { if (j < wid) woff += wsum[j]; }
    int c = carry;
    if (i < NN) { int ex = c + woff + s - v; rowptr[i] = ex; cursor[i] = ex; }
    __syncthreads();
    if (t == 1023) carry = c + woff + s;
    __syncthreads();
  }
  if (threadIdx.x == 0) rowptr[NN] = carry;
}

// ---------------- K: 16B edge records {col(bits), 0, v0, v1}  (v = pseudo*4, raw)
__global__ void k_rec(const int* __restrict__ ei, const float* __restrict__ pseudo,
                      int* __restrict__ cursor, float4* __restrict__ recs) {
  int e = blockIdx.x * 256 + threadIdx.x;
  if (e >= EE) return;
  int row = ei[e], col = ei[EE + e];
  float2 pv = ((const float2*)pseudo)[e];
  int slot = atomicAdd(&cursor[row], 1);
  float4 r;
  r.x = __uint_as_float((unsigned)col);
  r.y = 0.0f;
  r.z = pv.x * 4.0f;
  r.w = pv.y * 4.0f;
  recs[slot] = r;
}

// ---------------- K: main fused. 1 block = 16 nodes; wave w owns node nb+w.
__global__ __launch_bounds__(1024) void k_main(
    const float4* __restrict__ recs, const int* __restrict__ rowptr,
    const float* __restrict__ x, const ushort_t* __restrict__ wt,
    const float* __restrict__ root, const float* __restrict__ bias,
    float* __restrict__ out) {
  __shared__ ushort_t accS[NPB * ASTB];   // 53.5 KB, bf16, MFMA-A layout
  __shared__ float    outp[4 * NPB * 64]; // 16 KB, per-kh partials
  __shared__ float    sinv[NPB];
  const int tid = threadIdx.x;
  const int lane = tid & 63;
  const int w = tid >> 6;                 // wave id = node-in-block
  const int nb = blockIdx.x * NPB;
  const int node = nb + w;

  const int eb = rowptr[node], ee = rowptr[node + 1];
  if (lane == 0) sinv[w] = 1.0f / (float)max(ee - eb, 1);
  accS[w * ASTB + 1600 + lane] = 0;       // zero the MFMA k-pad slice

  const int m15 = lane & 15, quad = lane >> 4;
  // basis (r,c) constants per lane for the two M-tiles; kp>=25 rows -> hat()=0 naturally
  const float r0f = (float)(m15 / 5),        c0f = (float)(m15 % 5);
  const float r1f = (float)((16 + m15) / 5), c1f = (float)((16 + m15) % 5);

  f32x4 acc[2][4];                        // [mtile][ntile], 32 VGPRs
#pragma unroll
  for (int a = 0; a < 2; ++a)
#pragma unroll
    for (int b = 0; b < 4; ++b) acc[a][b] = (f32x4){0.f, 0.f, 0.f, 0.f};

  for (int e0 = eb; e0 < ee; e0 += 32) {  // K=32 edge chunks
    float a0f[8], a1f[8], bfv[4][8];
#pragma unroll
    for (int j = 0; j < 8; ++j) {
      int e = e0 + quad * 8 + j;          // fragment k-index = quad*8+j (R8-validated)
      int ec = min(e, ee - 1);
      float4 rc = recs[ec];
      float msk = (e < ee) ? 1.0f : 0.0f;
      float v0 = rc.z, v1 = rc.w;
      float h00 = fmaxf(0.f, 1.f - fabsf(v0 - r0f));
      float h01 = fmaxf(0.f, 1.f - fabsf(v1 - c0f));
      float h10 = fmaxf(0.f, 1.f - fabsf(v0 - r1f));
      float h11 = fmaxf(0.f, 1.f - fabsf(v1 - c1f));
      a0f[j] = h00 * h01 * msk;
      a1f[j] = h10 * h11 * msk;
      const float* xr = x + (size_t)__float_as_uint(rc.x) * 64 + m15;
      bfv[0][j] = xr[0];                  // B-frag: X[f][e], 16-lane 64B segments
      bfv[1][j] = xr[16];
      bfv[2][j] = xr[32];
      bfv[3][j] = xr[48];
    }
    S8 aT0, aT1, bT[4];
#pragma unroll
    for (int p = 0; p < 4; ++p) {
      aT0.u[p] = pk2bf(a0f[2 * p], a0f[2 * p + 1]);
      aT1.u[p] = pk2bf(a1f[2 * p], a1f[2 * p + 1]);
#pragma unroll
      for (int t = 0; t < 4; ++t) bT[t].u[p] = pk2bf(bfv[t][2 * p], bfv[t][2 * p + 1]);
    }
#pragma unroll
    for (int t = 0; t < 4; ++t) {
      acc[0][t] = __builtin_amdgcn_mfma_f32_16x16x32_bf16(aT0.s, bT[t].s, acc[0][t], 0, 0, 0);
      acc[1][t] = __builtin_amdgcn_mfma_f32_16x16x32_bf16(aT1.s, bT[t].s, acc[1][t], 0, 0, 0);
    }
  }

  // spill acc -> accS; D layout: kp = mt*16 + quad*4 + r, f = nt*16 + m15
#pragma unroll
  for (int mt = 0; mt < 2; ++mt)
#pragma unroll
    for (int r = 0; r < 4; ++r) {
      int kp = mt * 16 + quad * 4 + r;
      if (kp < 25) {
#pragma unroll
        for (int nt = 0; nt < 4; ++nt)
          accS[w * ASTB + kp * 64 + nt * 16 + m15] = f2bf(acc[mt][nt][r]);
      }
    }
  __syncthreads();

  {  // MFMA epilogue (R8-verified): D[16 nodes][64 out] = accS[16][1664] @ wt^T
    const int ntile = w & 3, kh = w >> 2;
    const int m = lane & 15, quad2 = lane >> 4;
    const int nn2 = ntile * 16 + m;
    f32x4 d = {0.0f, 0.0f, 0.0f, 0.0f};
    const ushort_t* ab = &accS[m * ASTB + kh * 416 + quad2 * 8];
    const ushort_t* wb = &wt[(size_t)nn2 * KD + kh * 416 + quad2 * 8];
    for (int kk = 0; kk < 13; ++kk) {
      short8 af = *(const short8*)(ab + kk * 32);
      short8 bf = *(const short8*)(wb + kk * 32);
      d = __builtin_amdgcn_mfma_f32_16x16x32_bf16(af, bf, d, 0, 0, 0);
    }
#pragma unroll
    for (int r = 0; r < 4; ++r)
      outp[kh * (NPB * 64) + (quad2 * 4 + r) * 64 + ntile * 16 + m] = d[r];
  }
  __syncthreads();

  {  // final: sum 4 kh partials, + exact fp32 root
    float conv = outp[0 * (NPB * 64) + w * 64 + lane]
               + outp[1 * (NPB * 64) + w * 64 + lane]
               + outp[2 * (NPB * 64) + w * 64 + lane]
               + outp[3 * (NPB * 64) + w * 64 + lane];
    const float* xrow = &x[(size_t)node * 64];
    float r0 = bias[lane], r1 = 0.f, r2 = 0.f, r3 = 0.f;
    for (int i = 0; i < 64; i += 4) {
      r0 += xrow[i]     * root[(size_t)i * 64 + lane];
      r1 += xrow[i + 1] * root[(size_t)(i + 1) * 64 + lane];
      r2 += xrow[i + 2] * root[(size_t)(i + 2) * 64 + lane];
      r3 += xrow[i + 3] * root[(size_t)(i + 3) * 64 + lane];
    }
    out[(size_t)node * 64 + lane] = conv * sinv[w] + ((r0 + r1) + (r2 + r3));
  }
}

// ---------------- sentinel: unambiguous "workspace too small" signature
__global__ void k_sentinel(float* __restrict__ out) {
  int i = blockIdx.x * 256 + threadIdx.x;
  if (i < NN * 64) out[i] = 1000.0f;
}

extern "C" void kernel_launch(void* const* d_in, const int* in_sizes, int n_in,
                              void* d_out, int out_size, void* d_ws, size_t ws_size,
                              hipStream_t stream) {
  const float* x      = (const float*)d_in[0];
  const int*   ei     = (const int*)d_in[1];
  const float* pseudo = (const float*)d_in[2];
  const float* w      = (const float*)d_in[3];
  const float* root   = (const float*)d_in[4];
  const float* bias   = (const float*)d_in[5];
  float* out = (float*)d_out;
  (void)in_sizes; (void)n_in; (void)out_size;

  char* ws = (char*)d_ws;
  size_t off = 0;
  auto alloc = [&](size_t bytes) { size_t r = off; off += (bytes + 511) & ~(size_t)511; return r; };
  ushort_t* wt     = (ushort_t*)(ws + alloc((size_t)64 * KD * 2));   // 212,992 B
  int*      rowptr = (int*)(ws + alloc((size_t)(NN + 1) * 4));
  int*      cursor = (int*)(ws + alloc((size_t)NN * 4));
  int*      deg    = (int*)(ws + alloc((size_t)NN * 4));
  float4*   recs   = (float4*)(ws + alloc((size_t)EE * 16));         // 25.6 MB
  if (ws_size < off) {  // ~26.4 MB needed (known available from R5/R6)
    k_sentinel<<<(NN * 64 + 255) / 256, 256, 0, stream>>>(out);
    return;
  }

  k_wt<<<(64 * KD + 255) / 256, 256, 0, stream>>>(w, wt);
  hipMemsetAsync(deg, 0, (size_t)NN * 4, stream);
  k_deg<<<(EE + 255) / 256, 256, 0, stream>>>(ei, deg);
  k_scan<<<1, 1024, 0, stream>>>(deg, rowptr, cursor);
  k_rec<<<(EE + 255) / 256, 256, 0, stream>>>(ei, pseudo, cursor, recs);
  k_main<<<NN / NPB, 1024, 0, stream>>>(recs, rowptr, x, wt, root, bias, out);
}

// Round 10
// 421.906 us; speedup vs baseline: 6.9953x; 1.2347x over previous
//
#include <hip/hip_runtime.h>
#include <hip/hip_fp16.h>
#include <hip/hip_bf16.h>

// SplineConv MI355X (gfx950). fp32 in/out. R10:
//  - root folded into MFMA epilogue (accS pad slice = x*deg, wt tail = root^T)
//  - 8B edge records {col, fp16 v0|v1} (halve k_rec scatter + k_main gather)
//  - multi-block scan (3 tiny kernels) replacing 49-round single-block scan
// Scatter-as-GEMM per node wave (R9-validated), no LDS atomics anywhere.

#define NN   50000
#define EE   1600000
#define NPB  16
#define KD   1664            // 26*64: 25 conv slices + root slice
#define ASTB 1672            // accS row stride (bf16 elems)
#define SB   49              // scan blocks (49*1024 >= 50000)

typedef unsigned short ushort_t;
typedef __attribute__((ext_vector_type(8))) short short8;
typedef __attribute__((ext_vector_type(4))) float f32x4;

static __device__ __forceinline__ ushort_t f2bf(float f) {
  union { float f; unsigned u; } v; v.f = f;
  return (ushort_t)((v.u + 0x7fffu + ((v.u >> 16) & 1u)) >> 16);  // RNE
}
static __device__ __forceinline__ unsigned pk2bf(float a, float b) {
  __hip_bfloat162 h = __float22bfloat162_rn(make_float2(a, b));   // v_cvt_pk_bf16_f32
  union { __hip_bfloat162 h; unsigned u; } cv; cv.h = h; return cv.u;
}
union S8 { short8 s; unsigned u[4]; };

// ---------------- K: wt[o*1664+k]: k<1600 -> weight[k*64+o]; tail -> root[(k-1600)*64+o]
__global__ void k_wt(const float* __restrict__ w, const float* __restrict__ root,
                     ushort_t* __restrict__ wt) {
  int idx = blockIdx.x * 256 + threadIdx.x;
  if (idx >= 64 * KD) return;
  int o = idx / KD, k = idx - o * KD;
  wt[idx] = (k < 1600) ? f2bf(w[k * 64 + o]) : f2bf(root[(k - 1600) * 64 + o]);
}

// ---------------- K: degree count
__global__ void k_deg(const int* __restrict__ ei, int* __restrict__ deg) {
  int e = blockIdx.x * 256 + threadIdx.x;
  if (e < EE) atomicAdd(&deg[ei[e]], 1);
}

// ---------------- scan (3 kernels): per-block sums -> scan sums -> apply
__global__ __launch_bounds__(1024) void k_scan1(const int* __restrict__ deg,
                                                int* __restrict__ bsum) {
  __shared__ int ws[16];
  int t = threadIdx.x, i = blockIdx.x * 1024 + t;
  int v = (i < NN) ? deg[i] : 0;
#pragma unroll
  for (int off = 32; off; off >>= 1) v += __shfl_down(v, off);
  if ((t & 63) == 0) ws[t >> 6] = v;
  __syncthreads();
  if (t == 0) {
    int s = 0;
#pragma unroll
    for (int j = 0; j < 16; ++j) s += ws[j];
    bsum[blockIdx.x] = s;
  }
}
__global__ void k_scan2(const int* __restrict__ bsum, int* __restrict__ boff,
                        int* __restrict__ rowptr) {
  if (threadIdx.x == 0) {
    int s = 0;
    for (int b = 0; b < SB; ++b) { boff[b] = s; s += bsum[b]; }
    rowptr[NN] = s;
  }
}
__global__ __launch_bounds__(1024) void k_scan3(const int* __restrict__ deg,
                                                const int* __restrict__ boff,
                                                int* __restrict__ rowptr,
                                                int* __restrict__ cursor) {
  __shared__ int ws[16];
  int t = threadIdx.x, lane = t & 63, wid = t >> 6;
  int i = blockIdx.x * 1024 + t;
  int v = (i < NN) ? deg[i] : 0;
  int s = v;
#pragma unroll
  for (int off = 1; off < 64; off <<= 1) {
    int u = __shfl_up(s, off);
    if (lane >= off) s += u;
  }
  if (lane == 63) ws[wid] = s;
  __syncthreads();
  int woff = 0;
#pragma unroll
  for (int j = 0; j < 16; ++j) { if (j < wid) woff += ws[j]; }
  int ex = boff[blockIdx.x] + woff + s - v;
  if (i < NN) { rowptr[i] = ex; cursor[i] = ex; }
}

// ---------------- K: 8B edge records {col, fp16(v0)|fp16(v1)<<16}
__global__ void k_rec(const int* __restrict__ ei, const float* __restrict__ pseudo,
                      int* __restrict__ cursor, uint2* __restrict__ recs) {
  int e = blockIdx.x * 256 + threadIdx.x;
  if (e >= EE) return;
  int row = ei[e], col = ei[EE + e];
  float2 pv = ((const float2*)pseudo)[e];
  int slot = atomicAdd(&cursor[row], 1);
  unsigned h0 = __half_as_ushort(__float2half(pv.x * 4.0f));
  unsigned h1 = __half_as_ushort(__float2half(pv.y * 4.0f));
  recs[slot] = make_uint2((unsigned)col, h0 | (h1 << 16));
}

// ---------------- K: main fused. 1 block = 16 nodes; wave w owns node nb+w.
__global__ __launch_bounds__(1024) void k_main(
    const uint2* __restrict__ recs, const int* __restrict__ rowptr,
    const float* __restrict__ x, const ushort_t* __restrict__ wt,
    const float* __restrict__ bias, float* __restrict__ out) {
  __shared__ ushort_t accS[NPB * ASTB];   // 53.5 KB, bf16, MFMA-A layout
  __shared__ float    outp[4 * NPB * 64]; // 16 KB, per-kh partials
  __shared__ float    sinv[NPB];
  const int tid = threadIdx.x;
  const int lane = tid & 63;
  const int w = tid >> 6;                 // wave id = node-in-block
  const int nb = blockIdx.x * NPB;
  const int node = nb + w;

  const int eb = rowptr[node], ee = rowptr[node + 1];
  const float dcf = (float)max(ee - eb, 1);
  if (lane == 0) sinv[w] = 1.0f / dcf;
  // root slice: accS[w][1600+i] = bf16(x[node][i] * dc); (x*dc)@root / dc = x@root
  accS[w * ASTB + 1600 + lane] = f2bf(x[(size_t)node * 64 + lane] * dcf);

  const int m15 = lane & 15, quad = lane >> 4;
  // basis (r,c) per lane for two M-tiles; kp>=25 rows -> hat()=0 naturally
  const float r0f = (float)(m15 / 5),        c0f = (float)(m15 % 5);
  const float r1f = (float)((16 + m15) / 5), c1f = (float)((16 + m15) % 5);

  f32x4 acc[2][4];                        // [mtile][ntile]
#pragma unroll
  for (int a = 0; a < 2; ++a)
#pragma unroll
    for (int b = 0; b < 4; ++b) acc[a][b] = (f32x4){0.f, 0.f, 0.f, 0.f};

  for (int e0 = eb; e0 < ee; e0 += 32) {  // K=32 edge chunks
    float a0f[8], a1f[8], bfv[4][8];
#pragma unroll
    for (int j = 0; j < 8; ++j) {
      int e = e0 + quad * 8 + j;          // fragment k-index = quad*8+j (R9-validated)
      int ec = min(e, ee - 1);
      uint2 rc = recs[ec];
      float msk = (e < ee) ? 1.0f : 0.0f;
      float v0 = __half2float(__ushort_as_half((ushort_t)(rc.y & 0xFFFFu)));
      float v1 = __half2float(__ushort_as_half((ushort_t)(rc.y >> 16)));
      float h00 = fmaxf(0.f, 1.f - fabsf(v0 - r0f));
      float h01 = fmaxf(0.f, 1.f - fabsf(v1 - c0f));
      float h10 = fmaxf(0.f, 1.f - fabsf(v0 - r1f));
      float h11 = fmaxf(0.f, 1.f - fabsf(v1 - c1f));
      a0f[j] = h00 * h01 * msk;
      a1f[j] = h10 * h11 * msk;
      const float* xr = x + (size_t)rc.x * 64 + m15;
      bfv[0][j] = xr[0];                  // B-frag: X[f][e], 16-lane 64B segments
      bfv[1][j] = xr[16];
      bfv[2][j] = xr[32];
      bfv[3][j] = xr[48];
    }
    S8 aT0, aT1, bT[4];
#pragma unroll
    for (int p = 0; p < 4; ++p) {
      aT0.u[p] = pk2bf(a0f[2 * p], a0f[2 * p + 1]);
      aT1.u[p] = pk2bf(a1f[2 * p], a1f[2 * p + 1]);
#pragma unroll
      for (int t = 0; t < 4; ++t) bT[t].u[p] = pk2bf(bfv[t][2 * p], bfv[t][2 * p + 1]);
    }
#pragma unroll
    for (int t = 0; t < 4; ++t) {
      acc[0][t] = __builtin_amdgcn_mfma_f32_16x16x32_bf16(aT0.s, bT[t].s, acc[0][t], 0, 0, 0);
      acc[1][t] = __builtin_amdgcn_mfma_f32_16x16x32_bf16(aT1.s, bT[t].s, acc[1][t], 0, 0, 0);
    }
  }

  // spill acc -> accS; D layout: kp = mt*16 + quad*4 + r, f = nt*16 + m15
#pragma unroll
  for (int mt = 0; mt < 2; ++mt)
#pragma unroll
    for (int r = 0; r < 4; ++r) {
      int kp = mt * 16 + quad * 4 + r;
      if (kp < 25) {
#pragma unroll
        for (int nt = 0; nt < 4; ++nt)
          accS[w * ASTB + kp * 64 + nt * 16 + m15] = f2bf(acc[mt][nt][r]);
      }
    }
  __syncthreads();

  {  // MFMA epilogue (R8/R9-verified): D[16 nodes][64] = accS[16][1664] @ wt^T
    const int ntile = w & 3, kh = w >> 2;
    const int m = lane & 15, quad2 = lane >> 4;
    const int nn2 = ntile * 16 + m;
    f32x4 d = {0.0f, 0.0f, 0.0f, 0.0f};
    const ushort_t* ab = &accS[m * ASTB + kh * 416 + quad2 * 8];
    const ushort_t* wb = &wt[(size_t)nn2 * KD + kh * 416 + quad2 * 8];
    for (int kk = 0; kk < 13; ++kk) {
      short8 af = *(const short8*)(ab + kk * 32);
      short8 bf = *(const short8*)(wb + kk * 32);
      d = __builtin_amdgcn_mfma_f32_16x16x32_bf16(af, bf, d, 0, 0, 0);
    }
#pragma unroll
    for (int r = 0; r < 4; ++r)
      outp[kh * (NPB * 64) + (quad2 * 4 + r) * 64 + ntile * 16 + m] = d[r];
  }
  __syncthreads();

  {  // final: out = (conv + x*dc@root) * (1/dc) + bias
    float conv = outp[0 * (NPB * 64) + w * 64 + lane]
               + outp[1 * (NPB * 64) + w * 64 + lane]
               + outp[2 * (NPB * 64) + w * 64 + lane]
               + outp[3 * (NPB * 64) + w * 64 + lane];
    out[(size_t)node * 64 + lane] = conv * sinv[w] + bias[lane];
  }
}

// ---------------- sentinel: unambiguous "workspace too small" signature
__global__ void k_sentinel(float* __restrict__ out) {
  int i = blockIdx.x * 256 + threadIdx.x;
  if (i < NN * 64) out[i] = 1000.0f;
}

extern "C" void kernel_launch(void* const* d_in, const int* in_sizes, int n_in,
                              void* d_out, int out_size, void* d_ws, size_t ws_size,
                              hipStream_t stream) {
  const float* x      = (const float*)d_in[0];
  const int*   ei     = (const int*)d_in[1];
  const float* pseudo = (const float*)d_in[2];
  const float* w      = (const float*)d_in[3];
  const float* root   = (const float*)d_in[4];
  const float* bias   = (const float*)d_in[5];
  float* out = (float*)d_out;
  (void)in_sizes; (void)n_in; (void)out_size;

  char* ws = (char*)d_ws;
  size_t off = 0;
  auto alloc = [&](size_t bytes) { size_t r = off; off += (bytes + 511) & ~(size_t)511; return r; };
  ushort_t* wt     = (ushort_t*)(ws + alloc((size_t)64 * KD * 2));   // 212,992 B
  int*      rowptr = (int*)(ws + alloc((size_t)(NN + 1) * 4));
  int*      cursor = (int*)(ws + alloc((size_t)NN * 4));
  int*      deg    = (int*)(ws + alloc((size_t)NN * 4));
  int*      bsum   = (int*)(ws + alloc((size_t)SB * 4));
  int*      boff   = (int*)(ws + alloc((size_t)SB * 4));
  uint2*    recs   = (uint2*)(ws + alloc((size_t)EE * 8));           // 12.8 MB
  if (ws_size < off) {  // ~13.6 MB needed (known available from R5/R6)
    k_sentinel<<<(NN * 64 + 255) / 256, 256, 0, stream>>>(out);
    return;
  }

  k_wt<<<(64 * KD + 255) / 256, 256, 0, stream>>>(w, root, wt);
  hipMemsetAsync(deg, 0, (size_t)NN * 4, stream);
  k_deg<<<(EE + 255) / 256, 256, 0, stream>>>(ei, deg);
  k_scan1<<<SB, 1024, 0, stream>>>(deg, bsum);
  k_scan2<<<1, 64, 0, stream>>>(bsum, boff, rowptr);
  k_scan3<<<SB, 1024, 0, stream>>>(deg, boff, rowptr, cursor);
  k_rec<<<(EE + 255) / 256, 256, 0, stream>>>(ei, pseudo, cursor, recs);
  k_main<<<NN / NPB, 1024, 0, stream>>>(recs, rowptr, x, wt, bias, out);
}

// Round 11
// 348.251 us; speedup vs baseline: 8.4748x; 1.2115x over previous
//
#include <hip/hip_runtime.h>
#include <hip/hip_fp16.h>
#include <hip/hip_bf16.h>

// SplineConv MI355X (gfx950). fp32 in/out. R11:
//  - single-pass bucketed edge placement (CAP=56/node) + exact overflow list;
//    deletes k_deg + 3 scan kernels + one edge_index pass (8 -> 5 dispatches)
//  - bf16 x copy for the B-fragment gather (halves gather bytes; fits per-XCD L2)
//    gated on ws_size, falls back to fp32 gather
// Scatter-as-GEMM per node wave + root-folded MFMA epilogue (R9/R10-validated).

#define NN    50000
#define EE    1600000
#define NPB   16
#define KD    1664           // 26*64: 25 conv slices + root slice
#define ASTB  1672           // accS row stride (bf16 elems)
#define CAP   56             // bucket capacity per node (Poisson(32) max ~60; tail -> OF)
#define OFCAP 16384

typedef unsigned short ushort_t;
typedef __attribute__((ext_vector_type(8))) short short8;
typedef __attribute__((ext_vector_type(4))) float f32x4;

static __device__ __forceinline__ ushort_t f2bf(float f) {
  union { float f; unsigned u; } v; v.f = f;
  return (ushort_t)((v.u + 0x7fffu + ((v.u >> 16) & 1u)) >> 16);  // RNE
}
static __device__ __forceinline__ unsigned pk2bf(float a, float b) {
  __hip_bfloat162 h = __float22bfloat162_rn(make_float2(a, b));   // v_cvt_pk_bf16_f32
  union { __hip_bfloat162 h; unsigned u; } cv; cv.h = h; return cv.u;
}
union S8 { short8 s; unsigned u[4]; };

// ---------------- K: wt[o*1664+k]: k<1600 -> weight[k*64+o]; tail -> root[(k-1600)*64+o]
__global__ void k_wt(const float* __restrict__ w, const float* __restrict__ root,
                     ushort_t* __restrict__ wt) {
  int idx = blockIdx.x * 256 + threadIdx.x;
  if (idx >= 64 * KD) return;
  int o = idx / KD, k = idx - o * KD;
  wt[idx] = (k < 1600) ? f2bf(w[k * 64 + o]) : f2bf(root[(k - 1600) * 64 + o]);
}

// ---------------- K: xb = bf16(x)  (RNE -- numerically identical to pk2bf path)
__global__ void k_xb(const float* __restrict__ x, ushort_t* __restrict__ xb) {
  int i = blockIdx.x * 256 + threadIdx.x;
  if (i < NN * 64) xb[i] = f2bf(x[i]);
}

// ---------------- K: single-pass bucketed records {col, fp16(v0)|fp16(v1)<<16}
__global__ void k_rec(const int* __restrict__ ei, const float* __restrict__ pseudo,
                      int* __restrict__ cursor, uint2* __restrict__ recs,
                      uint4* __restrict__ ofl) {
  int e = blockIdx.x * 256 + threadIdx.x;
  if (e >= EE) return;
  int row = ei[e], col = ei[EE + e];
  float2 pv = ((const float2*)pseudo)[e];
  float v0 = pv.x * 4.0f, v1 = pv.y * 4.0f;
  int slot = atomicAdd(&cursor[row], 1);
  if (slot < CAP) {
    unsigned h0 = __half_as_ushort(__float2half(v0));
    unsigned h1 = __half_as_ushort(__float2half(v1));
    recs[row * CAP + slot] = make_uint2((unsigned)col, h0 | (h1 << 16));
  } else {
    int o = atomicAdd(&cursor[NN], 1);       // overflow counter lives at cursor[NN]
    if (o < OFCAP)
      ofl[o] = make_uint4((unsigned)row, (unsigned)col,
                          __float_as_uint(v0), __float_as_uint(v1));
  }
}

// ---------------- K: main fused. 1 block = 16 nodes; wave w owns node nb+w.
template <bool XBF>
__global__ __launch_bounds__(1024) void k_main(
    const uint2* __restrict__ recs, const int* __restrict__ cursor,
    const uint4* __restrict__ ofl,
    const float* __restrict__ x, const ushort_t* __restrict__ xb,
    const ushort_t* __restrict__ wt, const float* __restrict__ bias,
    float* __restrict__ out) {
  __shared__ ushort_t accS[NPB * ASTB];   // 53.5 KB, bf16, MFMA-A layout
  __shared__ float    outp[4 * NPB * 64]; // 16 KB, per-kh partials
  __shared__ float    sinv[NPB];
  const int tid = threadIdx.x;
  const int lane = tid & 63;
  const int w = tid >> 6;                 // wave id = node-in-block
  const int nb = blockIdx.x * NPB;
  const int node = nb + w;

  const int dg = cursor[node];            // true degree (may exceed CAP)
  const int m = min(dg, CAP);             // edges in bucket
  const float dcf = (float)max(dg, 1);
  if (lane == 0) sinv[w] = 1.0f / dcf;
  // root slice: accS[w][1600+i] = bf16(x[node][i] * dc); (x*dc)@root / dc = x@root
  accS[w * ASTB + 1600 + lane] = f2bf(x[(size_t)node * 64 + lane] * dcf);

  const int m15 = lane & 15, quad = lane >> 4;
  const float r0f = (float)(m15 / 5),        c0f = (float)(m15 % 5);
  const float r1f = (float)((16 + m15) / 5), c1f = (float)((16 + m15) % 5);

  f32x4 acc[2][4];                        // [mtile][ntile]
#pragma unroll
  for (int a = 0; a < 2; ++a)
#pragma unroll
    for (int b = 0; b < 4; ++b) acc[a][b] = (f32x4){0.f, 0.f, 0.f, 0.f};

  const uint2* bket = recs + (size_t)node * CAP;
  for (int e0 = 0; e0 < m; e0 += 32) {    // K=32 edge chunks
    float a0f[8], a1f[8];
    float bfv[4][8];
    unsigned bu[4][8];
#pragma unroll
    for (int j = 0; j < 8; ++j) {
      int e = e0 + quad * 8 + j;          // fragment k-index = quad*8+j (R9-validated)
      int ec = min(e, m - 1);
      uint2 rc = bket[ec];
      float msk = (e < m) ? 1.0f : 0.0f;
      float v0 = __half2float(__ushort_as_half((ushort_t)(rc.y & 0xFFFFu)));
      float v1 = __half2float(__ushort_as_half((ushort_t)(rc.y >> 16)));
      float h00 = fmaxf(0.f, 1.f - fabsf(v0 - r0f));
      float h01 = fmaxf(0.f, 1.f - fabsf(v1 - c0f));
      float h10 = fmaxf(0.f, 1.f - fabsf(v0 - r1f));
      float h11 = fmaxf(0.f, 1.f - fabsf(v1 - c1f));
      a0f[j] = h00 * h01 * msk;
      a1f[j] = h10 * h11 * msk;
      if (XBF) {
        const ushort_t* xr = xb + (size_t)rc.x * 64 + m15;
        bu[0][j] = xr[0];                 // 2B gathers from 6.4MB bf16 copy
        bu[1][j] = xr[16];
        bu[2][j] = xr[32];
        bu[3][j] = xr[48];
      } else {
        const float* xr = x + (size_t)rc.x * 64 + m15;
        bfv[0][j] = xr[0];
        bfv[1][j] = xr[16];
        bfv[2][j] = xr[32];
        bfv[3][j] = xr[48];
      }
    }
    S8 aT0, aT1, bT[4];
#pragma unroll
    for (int p = 0; p < 4; ++p) {
      aT0.u[p] = pk2bf(a0f[2 * p], a0f[2 * p + 1]);
      aT1.u[p] = pk2bf(a1f[2 * p], a1f[2 * p + 1]);
#pragma unroll
      for (int t = 0; t < 4; ++t)
        bT[t].u[p] = XBF ? (bu[t][2 * p] | (bu[t][2 * p + 1] << 16))
                         : pk2bf(bfv[t][2 * p], bfv[t][2 * p + 1]);
    }
#pragma unroll
    for (int t = 0; t < 4; ++t) {
      acc[0][t] = __builtin_amdgcn_mfma_f32_16x16x32_bf16(aT0.s, bT[t].s, acc[0][t], 0, 0, 0);
      acc[1][t] = __builtin_amdgcn_mfma_f32_16x16x32_bf16(aT1.s, bT[t].s, acc[1][t], 0, 0, 0);
    }
  }

  {  // overflow replay (rare; exact): one masked 1-edge chunk per matching entry
    int ofc = min(cursor[NN], OFCAP);
    for (int i = 0; i < ofc; ++i) {
      uint4 r = ofl[i];
      if ((int)r.x != node) continue;     // wave-uniform
      float v0 = __uint_as_float(r.z), v1 = __uint_as_float(r.w);
      float h00 = fmaxf(0.f, 1.f - fabsf(v0 - r0f));
      float h01 = fmaxf(0.f, 1.f - fabsf(v1 - c0f));
      float h10 = fmaxf(0.f, 1.f - fabsf(v0 - r1f));
      float h11 = fmaxf(0.f, 1.f - fabsf(v1 - c1f));
      float mk = (quad == 0) ? 1.0f : 0.0f;    // edge occupies k=0 only
      S8 aT0, aT1, bT[4];
#pragma unroll
      for (int p = 0; p < 4; ++p) { aT0.u[p] = 0; aT1.u[p] = 0; }
      aT0.u[0] = pk2bf(h00 * h01 * mk, 0.0f);
      aT1.u[0] = pk2bf(h10 * h11 * mk, 0.0f);
      const float* xr = x + (size_t)r.y * 64 + m15;
#pragma unroll
      for (int t = 0; t < 4; ++t) {
        float xv = xr[16 * t];
#pragma unroll
        for (int p = 0; p < 4; ++p) bT[t].u[p] = pk2bf(xv, xv);  // A zeros mask these
      }
#pragma unroll
      for (int t = 0; t < 4; ++t) {
        acc[0][t] = __builtin_amdgcn_mfma_f32_16x16x32_bf16(aT0.s, bT[t].s, acc[0][t], 0, 0, 0);
        acc[1][t] = __builtin_amdgcn_mfma_f32_16x16x32_bf16(aT1.s, bT[t].s, acc[1][t], 0, 0, 0);
      }
    }
  }

  // spill acc -> accS; D layout: kp = mt*16 + quad*4 + r, f = nt*16 + m15
#pragma unroll
  for (int mt = 0; mt < 2; ++mt)
#pragma unroll
    for (int r = 0; r < 4; ++r) {
      int kp = mt * 16 + quad * 4 + r;
      if (kp < 25) {
#pragma unroll
        for (int nt = 0; nt < 4; ++nt)
          accS[w * ASTB + kp * 64 + nt * 16 + m15] = f2bf(acc[mt][nt][r]);
      }
    }
  __syncthreads();

  {  // MFMA epilogue (R8-R10 verified): D[16 nodes][64] = accS[16][1664] @ wt^T
    const int ntile = w & 3, kh = w >> 2;
    const int m2 = lane & 15, quad2 = lane >> 4;
    const int nn2 = ntile * 16 + m2;
    f32x4 d = {0.0f, 0.0f, 0.0f, 0.0f};
    const ushort_t* ab = &accS[m2 * ASTB + kh * 416 + quad2 * 8];
    const ushort_t* wb = &wt[(size_t)nn2 * KD + kh * 416 + quad2 * 8];
    for (int kk = 0; kk < 13; ++kk) {
      short8 af = *(const short8*)(ab + kk * 32);
      short8 bf = *(const short8*)(wb + kk * 32);
      d = __builtin_amdgcn_mfma_f32_16x16x32_bf16(af, bf, d, 0, 0, 0);
    }
#pragma unroll
    for (int r = 0; r < 4; ++r)
      outp[kh * (NPB * 64) + (quad2 * 4 + r) * 64 + ntile * 16 + m2] = d[r];
  }
  __syncthreads();

  {  // final: out = (conv + x*dc@root) * (1/dc) + bias
    float conv = outp[0 * (NPB * 64) + w * 64 + lane]
               + outp[1 * (NPB * 64) + w * 64 + lane]
               + outp[2 * (NPB * 64) + w * 64 + lane]
               + outp[3 * (NPB * 64) + w * 64 + lane];
    out[(size_t)node * 64 + lane] = conv * sinv[w] + bias[lane];
  }
}

// ---------------- sentinel: unambiguous "workspace too small" signature
__global__ void k_sentinel(float* __restrict__ out) {
  int i = blockIdx.x * 256 + threadIdx.x;
  if (i < NN * 64) out[i] = 1000.0f;
}

extern "C" void kernel_launch(void* const* d_in, const int* in_sizes, int n_in,
                              void* d_out, int out_size, void* d_ws, size_t ws_size,
                              hipStream_t stream) {
  const float* x      = (const float*)d_in[0];
  const int*   ei     = (const int*)d_in[1];
  const float* pseudo = (const float*)d_in[2];
  const float* w      = (const float*)d_in[3];
  const float* root   = (const float*)d_in[4];
  const float* bias   = (const float*)d_in[5];
  float* out = (float*)d_out;
  (void)in_sizes; (void)n_in; (void)out_size;

  char* ws = (char*)d_ws;
  size_t off = 0;
  auto alloc = [&](size_t bytes) { size_t r = off; off += (bytes + 511) & ~(size_t)511; return r; };
  ushort_t* wt     = (ushort_t*)(ws + alloc((size_t)64 * KD * 2));     // 213 KB
  int*      cursor = (int*)(ws + alloc((size_t)(NN + 1) * 4));         // cursor + ofc
  uint4*    ofl    = (uint4*)(ws + alloc((size_t)OFCAP * 16));         // 256 KB
  uint2*    recs   = (uint2*)(ws + alloc((size_t)NN * CAP * 8));       // 22.4 MB
  size_t baseNeed  = off;
  ushort_t* xb     = (ushort_t*)(ws + alloc((size_t)NN * 64 * 2));     // 6.4 MB (optional)
  size_t fullNeed  = off;

  if (ws_size < baseNeed) {
    k_sentinel<<<(NN * 64 + 255) / 256, 256, 0, stream>>>(out);
    return;
  }
  const bool useXB = (ws_size >= fullNeed);

  k_wt<<<(64 * KD + 255) / 256, 256, 0, stream>>>(w, root, wt);
  hipMemsetAsync(cursor, 0, (size_t)(NN + 1) * 4, stream);
  if (useXB) k_xb<<<(NN * 64 + 255) / 256, 256, 0, stream>>>(x, xb);
  k_rec<<<(EE + 255) / 256, 256, 0, stream>>>(ei, pseudo, cursor, recs, ofl);
  if (useXB)
    k_main<true><<<NN / NPB, 1024, 0, stream>>>(recs, cursor, ofl, x, xb, wt, bias, out);
  else
    k_main<false><<<NN / NPB, 1024, 0, stream>>>(recs, cursor, ofl, x, xb, wt, bias, out);
}